// Round 4
// baseline (541.477 us; speedup 1.0000x reference)
//
#include <hip/hip_runtime.h>
#include <hip/hip_bf16.h>

typedef float f32x4 __attribute__((ext_vector_type(4)));
typedef short s16x4 __attribute__((ext_vector_type(4)));
typedef short s16x8 __attribute__((ext_vector_type(8)));

#define HWSZ 9216   // 96*96
#define NC 512
#define NO 128
#define NBATCH 16

__device__ __forceinline__ unsigned short f2bf(float f) {
    unsigned u = __float_as_uint(f);
    u = u + 0x7FFFu + ((u >> 16) & 1u);   // RNE, inputs are finite
    return (unsigned short)(u >> 16);
}
__device__ __forceinline__ float bf2f(unsigned short h) {
    return __uint_as_float(((unsigned)h) << 16);
}

// ---------------------------------------------------------------------------
// Prepass: W (128x512 fp32) -> bf16 fragments ordered for direct A-frag loads.
// Tile (ks, otg): lane l holds W[o = otg*16 + (l&15)][c = ks*32 + 8*(l>>4) + i]
// stored at Wp[(ks*8 + otg)*64 + l].  (m90-m97 verified fragment convention:
// A row = lane&15, k-octet = 8*(lane>>4), contiguous 8 k per lane.)
// ---------------------------------------------------------------------------
__global__ __launch_bounds__(64) void wprep_k(const float* __restrict__ W,
                                              s16x8* __restrict__ Wp) {
    const int bid = blockIdx.x;          // 0..127 = ks*8 + otg
    const int ks = bid >> 3, otg = bid & 7;
    const int l = threadIdx.x;
    const int o = otg * 16 + (l & 15);
    const int c = ks * 32 + 8 * (l >> 4);
    const float* src = W + o * NC + c;
    f32x4 w0 = *(const f32x4*)src;
    f32x4 w1 = *(const f32x4*)(src + 4);
    s16x8 r;
#pragma unroll
    for (int i = 0; i < 4; ++i) {
        r[i]     = (short)f2bf(w0[i]);
        r[4 + i] = (short)f2bf(w1[i]);
    }
    Wp[bid * 64 + l] = r;
}

// ---------------------------------------------------------------------------
// GEMM: feat[b,o,hw] = sum_c W[o,c] * x[b,c,hw] + bias[o], stored bf16.
// Block: 128 o  x 64 hw, K=512 in 16 steps of 32.
// 4 waves: wave wv -> wo = wv&1 (o half), whw = wv>>1 (hw half).
// x staged per K-step into a LINEAR [32 c][64 hw] bf16 LDS tile (coalesced
// 16B ds_write_b128 per thread).  B-frags read with plain scalar ds_read_u16
// (8 per frag, stride 128 B): lane (g=lane>>4, li=lane&15) needs
// x[c = 8g+i][hw = whw*32 + ht*16 + li] — the m92-verified B layout
// (col = lane&15, k = 8*(lane>>4)+i).  No inline asm; compiler waitcnts.
// ---------------------------------------------------------------------------
__global__ __launch_bounds__(256) void gemm_k(const float* __restrict__ x,
                                              const s16x8* __restrict__ Wp,
                                              const float* __restrict__ bias,
                                              unsigned short* __restrict__ feat) {
    __shared__ __align__(16) short xs[2048];   // [32 c][64 hw] bf16 = 4 KB
    const int bid = blockIdx.x;
    const int b   = bid / 144;
    const int hw0 = (bid % 144) * 64;
    const int tid = threadIdx.x;
    const int lane = tid & 63;
    const int wv   = tid >> 6;
    const int wo   = wv & 1;
    const int whw  = wv >> 1;
    const int g    = lane >> 4;
    const int li   = lane & 15;

    // staging assignment: c-row = tid>>3 (0..31), hw octet = tid&7
    const int sc = tid >> 3;
    const int f8 = tid & 7;
    const float* xptr = x + ((size_t)b * NC + sc) * HWSZ + hw0 + f8 * 8;
    short* wp = &xs[sc * 64 + f8 * 8];

    const s16x8* ap = Wp + (wo * 4) * 64 + lane;

    f32x4 acc[4][2] = {};

#pragma unroll 1
    for (int ks = 0; ks < 16; ++ks) {
        // global loads (issue early; latency hidden under barrier/staging)
        f32x4 xa = *(const f32x4*)xptr;
        f32x4 xb = *(const f32x4*)(xptr + 4);
        xptr += 32 * HWSZ;
        s16x8 a0 = ap[0], a1 = ap[64], a2 = ap[128], a3 = ap[192];
        ap += 512;

        __syncthreads();                 // previous step's LDS reads done
        s16x8 v;
#pragma unroll
        for (int i = 0; i < 4; ++i) {
            v[i]     = (short)f2bf(xa[i]);
            v[4 + i] = (short)f2bf(xb[i]);
        }
        *(s16x8*)wp = v;                 // ds_write_b128, contiguous 16 B
        __syncthreads();                 // tile visible

        s16x8 b0, b1;
#pragma unroll
        for (int i = 0; i < 8; ++i) {
            b0[i] = xs[(8 * g + i) * 64 + whw * 32 + li];
            b1[i] = xs[(8 * g + i) * 64 + whw * 32 + 16 + li];
        }

        acc[0][0] = __builtin_amdgcn_mfma_f32_16x16x32_bf16(a0, b0, acc[0][0], 0, 0, 0);
        acc[0][1] = __builtin_amdgcn_mfma_f32_16x16x32_bf16(a0, b1, acc[0][1], 0, 0, 0);
        acc[1][0] = __builtin_amdgcn_mfma_f32_16x16x32_bf16(a1, b0, acc[1][0], 0, 0, 0);
        acc[1][1] = __builtin_amdgcn_mfma_f32_16x16x32_bf16(a1, b1, acc[1][1], 0, 0, 0);
        acc[2][0] = __builtin_amdgcn_mfma_f32_16x16x32_bf16(a2, b0, acc[2][0], 0, 0, 0);
        acc[2][1] = __builtin_amdgcn_mfma_f32_16x16x32_bf16(a2, b1, acc[2][1], 0, 0, 0);
        acc[3][0] = __builtin_amdgcn_mfma_f32_16x16x32_bf16(a3, b0, acc[3][0], 0, 0, 0);
        acc[3][1] = __builtin_amdgcn_mfma_f32_16x16x32_bf16(a3, b1, acc[3][1], 0, 0, 0);
    }

    // epilogue: D[m][n]: n = lane&15 (hw), m = 4*(lane>>4) + i (o within tile)
    const size_t fbase = (size_t)b * NO * HWSZ;
#pragma unroll
    for (int ot = 0; ot < 4; ++ot) {
        const int ob = wo * 64 + ot * 16 + 4 * g;
        f32x4 bv = *(const f32x4*)(bias + ob);
#pragma unroll
        for (int ht = 0; ht < 2; ++ht) {
            f32x4 vv = acc[ot][ht] + bv;
            const size_t p = fbase + (size_t)ob * HWSZ + hw0 + (whw * 2 + ht) * 16 + li;
#pragma unroll
            for (int i = 0; i < 4; ++i)
                feat[p + (size_t)i * HWSZ] = f2bf(vv[i]);
        }
    }
}

// ---------------------------------------------------------------------------
// Pool: per (b,o) plane, 4x4 cell sums (24x24 cells) then combine to
// s=8 (3x3 cells), s=6 (4x4), s=3 (8x8), s=1. Record: [p1][p3 x9][p6 x36][p8 x64]
// ---------------------------------------------------------------------------
__global__ __launch_bounds__(256) void pool_k(const unsigned short* __restrict__ feat,
                                              float* __restrict__ pools) {
    const int bo = blockIdx.x;           // 0..2047
    const unsigned short* f = feat + (size_t)bo * HWSZ;
    __shared__ float cs[576];
    __shared__ float s3s[9];
    const int t = threadIdx.x;
    for (int cell = t; cell < 576; cell += 256) {
        const int cy = cell / 24, cx = cell % 24;
        const unsigned short* p = f + (cy * 4) * 96 + cx * 4;
        float s = 0.f;
#pragma unroll
        for (int r = 0; r < 4; ++r) {
            s16x4 q = *(const s16x4*)(p + r * 96);
            s += bf2f((unsigned short)q[0]) + bf2f((unsigned short)q[1]) +
                 bf2f((unsigned short)q[2]) + bf2f((unsigned short)q[3]);
        }
        cs[cell] = s;
    }
    __syncthreads();
    float* rec = pools + (size_t)bo * 110;
    if (t < 64) {                        // s=8: 3x3 cells each (12x12 elems)
        const int py = t >> 3, px = t & 7;
        float s = 0.f;
#pragma unroll
        for (int yy = 0; yy < 3; ++yy)
#pragma unroll
            for (int xx = 0; xx < 3; ++xx)
                s += cs[(py * 3 + yy) * 24 + px * 3 + xx];
        rec[46 + t] = s * (1.0f / 144.0f);
    } else if (t < 128) {                // s=6: 4x4 cells (16x16 elems)
        const int u = t - 64;
        if (u < 36) {
            const int py = u / 6, px = u % 6;
            float s = 0.f;
#pragma unroll
            for (int yy = 0; yy < 4; ++yy)
#pragma unroll
                for (int xx = 0; xx < 4; ++xx)
                    s += cs[(py * 4 + yy) * 24 + px * 4 + xx];
            rec[10 + u] = s * (1.0f / 256.0f);
        }
    } else if (t < 192) {                // s=3: 8x8 cells (32x32 elems)
        const int u = t - 128;
        if (u < 9) {
            const int py = u / 3, px = u % 3;
            float s = 0.f;
#pragma unroll
            for (int yy = 0; yy < 8; ++yy)
#pragma unroll
                for (int xx = 0; xx < 8; ++xx)
                    s += cs[(py * 8 + yy) * 24 + px * 8 + xx];
            rec[1 + u] = s * (1.0f / 1024.0f);
            s3s[u] = s;
        }
    }
    __syncthreads();
    if (t == 0) {
        float s = 0.f;
#pragma unroll
        for (int i = 0; i < 9; ++i) s += s3s[i];
        rec[0] = s * (1.0f / 9216.0f);
    }
}

// ---------------------------------------------------------------------------
// Output: out[b, si*128+o, h, w] = feat - bilinear_up(pool_si)
// Block per (b,o): pools + align-corners axis tables cached in LDS.
// ---------------------------------------------------------------------------
__global__ __launch_bounds__(256) void fuse_k(const unsigned short* __restrict__ feat,
                                              const float* __restrict__ pools,
                                              float* __restrict__ out) {
    const int bo = blockIdx.x;
    const int b = bo >> 7, o = bo & 127;
    __shared__ float P[110];
    __shared__ int   ti[3][96];
    __shared__ float tw[3][96];
    const int t = threadIdx.x;
    if (t < 110) P[t] = pools[(size_t)bo * 110 + t];
    if (t < 96) {
        const float scl[3] = {2.0f / 95.0f, 5.0f / 95.0f, 7.0f / 95.0f};
#pragma unroll
        for (int si = 0; si < 3; ++si) {
            float fy = (float)t * scl[si];
            int i0 = (int)fy;
            ti[si][t] = i0;
            tw[si][t] = fy - (float)i0;
        }
    }
    __syncthreads();
    const float p1 = P[0];
    const unsigned short* f = feat + (size_t)bo * HWSZ;
    float* o0 = out + ((size_t)b * 512 + o) * HWSZ;

    for (int k = 0; k < 36; ++k) {
        const int idx = k * 256 + t;
        const float fv = bf2f(f[idx]);
        const int h = idx / 96;
        const int wd = idx - h * 96;

        auto br = [&](int si, int S, int Poff) -> float {
            const int y0 = ti[si][h];  const float wy = tw[si][h];
            const int x0 = ti[si][wd]; const float wx = tw[si][wd];
            const int y1 = min(y0 + 1, S - 1);
            const int x1 = min(x0 + 1, S - 1);
            const float* Q = P + Poff;
            const float v00 = Q[y0 * S + x0], v01 = Q[y0 * S + x1];
            const float v10 = Q[y1 * S + x0], v11 = Q[y1 * S + x1];
            const float top = v00 + (v01 - v00) * wx;
            const float bot = v10 + (v11 - v10) * wx;
            return top + (bot - top) * wy;
        };

        o0[idx]                      = fv - p1;
        o0[idx + (size_t)128 * HWSZ] = fv - br(0, 3, 1);
        o0[idx + (size_t)256 * HWSZ] = fv - br(1, 6, 10);
        o0[idx + (size_t)384 * HWSZ] = fv - br(2, 8, 46);
    }
}

// ---------------------------------------------------------------------------
extern "C" void kernel_launch(void* const* d_in, const int* in_sizes, int n_in,
                              void* d_out, int out_size, void* d_ws, size_t ws_size,
                              hipStream_t stream) {
    const float* x    = (const float*)d_in[0];
    const float* W    = (const float*)d_in[1];
    const float* bias = (const float*)d_in[2];
    float* out = (float*)d_out;

    char* ws = (char*)d_ws;
    s16x8* Wp = (s16x8*)ws;                                        // 131072 B
    unsigned short* feat = (unsigned short*)(ws + 131072);         // 37748736 B
    float* pools = (float*)(ws + 131072 + 37748736);               // 901120 B

    wprep_k<<<128, 64, 0, stream>>>(W, Wp);
    gemm_k<<<2304, 256, 0, stream>>>(x, Wp, bias, feat);
    pool_k<<<2048, 256, 0, stream>>>(feat, pools);
    fuse_k<<<2048, 256, 0, stream>>>(feat, pools, out);
}